// Round 5
// baseline (103.256 us; speedup 1.0000x reference)
//
#include <hip/hip_runtime.h>
#include <hip/hip_bf16.h>
#include <stdint.h>

#define M_DIM 2048
#define N_DIM 4096
#define K_DIM 4096

#define NT 64  // K tiles of 64

typedef short short8 __attribute__((ext_vector_type(8)));
typedef float f32x4 __attribute__((ext_vector_type(4)));

typedef __attribute__((address_space(1))) unsigned int gu32;
typedef __attribute__((address_space(3))) unsigned int lu32;

// f32 -> bf16 round-to-nearest-even
__device__ static inline unsigned short f32_to_bf16(float f) {
  union { float f; unsigned int u; } v; v.f = f;
  unsigned int u = v.u;
  u += 0x7FFFu + ((u >> 16) & 1u);
  return (unsigned short)(u >> 16);
}

// ---- x: f32 [M][K] -> bf16 [M][K] ----
__global__ void cvt_x_kernel(const float* __restrict__ in, unsigned short* __restrict__ out) {
  size_t i = ((size_t)blockIdx.x * blockDim.x + threadIdx.x) * 8;
  f32x4 a = *(const f32x4*)(in + i);
  f32x4 b = *(const f32x4*)(in + i + 4);
  short8 o;
  o[0] = (short)f32_to_bf16(a[0]); o[1] = (short)f32_to_bf16(a[1]);
  o[2] = (short)f32_to_bf16(a[2]); o[3] = (short)f32_to_bf16(a[3]);
  o[4] = (short)f32_to_bf16(b[0]); o[5] = (short)f32_to_bf16(b[1]);
  o[6] = (short)f32_to_bf16(b[2]); o[7] = (short)f32_to_bf16(b[3]);
  *(short8*)(out + i) = o;
}

// ---- w: f32 [K][N] -> Bfrag bf16 in MFMA-fragment order ----
// Bfrag block (ng, kt) is 2KB: byte ch*256 + l*16 + e*2 = W[kt*64+ch*8+e][ng*16+l].
// A wave's B-fragment load (fragment n, k-slot ks) is then
//   base(ng,kt) + ks*1024 + lane*16   (one coalesced 1KB global_load_dwordx4).
__global__ void bfrag_w_kernel(const float* __restrict__ w, unsigned short* __restrict__ bf) {
  __shared__ unsigned short tile2[64][72];  // [col][k], padded: 144B row stride, 16B aligned
  int bn = blockIdx.x * 64;  // n block
  int bk = blockIdx.y * 64;  // k block
  int t = threadIdx.x;       // 256 threads
  int c4 = (t & 15) * 4;
  int r0t = t >> 4;
#pragma unroll
  for (int p = 0; p < 4; ++p) {
    int r = r0t + p * 16;  // k row
    f32x4 v = *(const f32x4*)(w + (size_t)(bk + r) * N_DIM + bn + c4);
    tile2[c4 + 0][r] = f32_to_bf16(v[0]);
    tile2[c4 + 1][r] = f32_to_bf16(v[1]);
    tile2[c4 + 2][r] = f32_to_bf16(v[2]);
    tile2[c4 + 3][r] = f32_to_bf16(v[3]);
  }
  __syncthreads();
  // write 4 ng-blocks x 2KB = 512 x 16B units; thread t does units t and t+256
#pragma unroll
  for (int pass = 0; pass < 2; ++pass) {
    int u = t + pass * 256;
    int ngL = u >> 7;          // 0..3
    int off = u & 127;         // ch*16 + l
    int ch = off >> 4, l = off & 15;
    short8 val = *(const short8*)&tile2[ngL * 16 + l][ch * 8];
    size_t base = ((size_t)((bn >> 4) + ngL) * 64 + (size_t)(bk >> 6)) * 2048;
    *(short8*)((char*)bf + base + (size_t)off * 16) = val;
  }
}

// ===================== GEMM (round 5): B direct-to-register =====================
// BM=128, BN=256, BK=64. 512 threads = 8 waves (2M x 4N), wave tile 64x64.
// A: LDS, 3 sides x 16KB = 48KB, XOR-swizzled, global_load_lds staged,
//    side t%3, stage t+2 into (t-1)%3 during body t (round-2/3 invariants).
// B: NO LDS. Fragment-ordered Bfrag in ws; each wave loads its 8 fragments
//    (4n x 2ks) for tile t+1 as coalesced 1KB global loads into ping-pong
//    register buffers bE/bO (static indexing; 2 tiles per loop iteration).
//    B is wave-private => no cross-wave publish needed; compiler inserts
//    precise vmcnt before the MFMA uses.
// Sync per tile: issue order in body t = [B(t+1) x8, A-stage(t+2) x2];
// top of tile t: s_waitcnt vmcnt(2) lgkmcnt(0)  (the 2 = A(t+2) stages;
// guarantees A(t),B(t) complete in any compiler ordering) + sched_barrier
// (rule: hipcc hoists reg-only ops past asm waits) + s_barrier (publish A).
// LDS port/tile drops 176KB -> 80KB (A reads 64KB + A staging 16KB).

__global__ __launch_bounds__(512) void gemm8_kernel(
    const unsigned short* __restrict__ A, const char* __restrict__ Bfrag,
    const float* __restrict__ bias, float* __restrict__ C) {
  __shared__ unsigned short smA[3 * 8192];  // 49152 B
  char* smemc = (char*)&smA[0];

  const int tid = threadIdx.x;
  const int lane = tid & 63;
  const int w = tid >> 6;
  const int wm = w >> 2, wn = w & 3;

  // 8x4 region remap for L2 locality (bijective over 256 blocks)
  const int id = blockIdx.x;
  const int x = id & 7, j = id >> 3;
  const int by = ((x >> 2) << 3) + (j >> 2);
  const int bx = ((x & 3) << 2) + (j & 3);
  const int r0 = by * 128, c0 = bx * 256;

  // ---- A staging precompute (pre-swizzled global source, linear LDS dest) ----
  const int l8 = lane >> 3, l7 = lane & 7;
  const int chunkE = ((l7 ^ l8) << 3);  // swizzled k-chunk (bf16 elems), row&7 == l8
  const unsigned short* Ag = A + (size_t)(r0 + w * 16 + l8) * K_DIM + chunkE;
  const int aL0 = w * 2048;  // byte offset of wave's A chunk within 16KB side

#define GL(gp, ldsoff) __builtin_amdgcn_global_load_lds((gu32*)(gp), (lu32*)(smemc + (ldsoff)), 16, 0, 0)
#define STAGE_A(t, sb)                                                \
  do {                                                                \
    GL(Ag + (size_t)(t) * 64, (sb) + aL0);                            \
    GL(Ag + (size_t)(t) * 64 + 8 * (size_t)K_DIM, (sb) + aL0 + 1024); \
  } while (0)

  // ---- B fragment pointers ----
  const int ngBase = (c0 >> 4) + wn * 4;
  const char* Bb = Bfrag + (size_t)ngBase * 64 * 2048 + (size_t)lane * 16;
  // fragment n, tile T, slot ks at: Bb + n*131072 + T*2048 + ks*1024

  // ---- A fragment-read precompute (ushort units within side) ----
  const int l15 = lane & 15, hi = lane >> 4;
  const int aR = (wm * 64 + l15) * 64;       // A row base
  const int slot0 = ((hi ^ l7) << 3);        // ks=0: chunk hi at slot hi^(row&7)
  const int slot1 = (((4 + hi) ^ l7) << 3);  // ks=1: chunk 4+hi

  f32x4 acc[4][4] = {};
  short8 bE[4][2], bO[4][2];

  // prologue: A(0) -> side0, B(0) -> bE, A(1) -> side1  (order matters for vmcnt)
  STAGE_A(0, 0);
#pragma unroll
  for (int n = 0; n < 4; ++n) {
    bE[n][0] = *(const short8*)(Bb + (size_t)n * 131072);
    bE[n][1] = *(const short8*)(Bb + (size_t)n * 131072 + 1024);
  }
  STAGE_A(1, 16384);

#define TILE_BODY(T, BCUR, BNXT)                                                                  \
  {                                                                                               \
    const int sE = cs * 8192;                                                                     \
    const int stB = (cs == 0 ? 2 : cs - 1) * 16384;                                               \
    if ((T) < NT - 1) asm volatile("s_waitcnt vmcnt(2) lgkmcnt(0)" ::: "memory");                 \
    else              asm volatile("s_waitcnt vmcnt(0) lgkmcnt(0)" ::: "memory");                 \
    __builtin_amdgcn_sched_barrier(0);                                                            \
    asm volatile("s_barrier" ::: "memory");                                                       \
    if ((T) + 1 < NT) {                                                                           \
      _Pragma("unroll") for (int n = 0; n < 4; ++n) {                                             \
        BNXT[n][0] = *(const short8*)(Bb + (size_t)n * 131072 + (size_t)((T) + 1) * 2048);        \
        BNXT[n][1] = *(const short8*)(Bb + (size_t)n * 131072 + (size_t)((T) + 1) * 2048 + 1024); \
      }                                                                                           \
    }                                                                                             \
    if ((T) + 2 < NT) { STAGE_A((T) + 2, stB); }                                                  \
    short8 a0[4], a1[4];                                                                          \
    _Pragma("unroll") for (int m = 0; m < 4; ++m)                                                 \
        a0[m] = *(const short8*)(smA + sE + aR + m * 1024 + slot0);                               \
    _Pragma("unroll") for (int m = 0; m < 4; ++m)                                                 \
        a1[m] = *(const short8*)(smA + sE + aR + m * 1024 + slot1);                               \
    __builtin_amdgcn_s_setprio(1);                                                                \
    _Pragma("unroll") for (int m = 0; m < 4; ++m)                                                 \
      _Pragma("unroll") for (int n = 0; n < 4; ++n)                                               \
          acc[m][n] = __builtin_amdgcn_mfma_f32_16x16x32_bf16(a0[m], BCUR[n][0], acc[m][n], 0, 0, 0); \
    _Pragma("unroll") for (int m = 0; m < 4; ++m)                                                 \
      _Pragma("unroll") for (int n = 0; n < 4; ++n)                                               \
          acc[m][n] = __builtin_amdgcn_mfma_f32_16x16x32_bf16(a1[m], BCUR[n][1], acc[m][n], 0, 0, 0); \
    __builtin_amdgcn_s_setprio(0);                                                                \
    cs = (cs == 2) ? 0 : cs + 1;                                                                  \
  }

  int cs = 0;
  for (int t2 = 0; t2 < NT; t2 += 2) {
    TILE_BODY(t2, bE, bO);      // even tile: consume bE, prefetch bO
    TILE_BODY(t2 + 1, bO, bE);  // odd tile: consume bO, prefetch bE
  }

  // ---- epilogue: fxp(y) + fxp(b), relu ----
  const float S = 65536.0f, IS = 1.0f / 65536.0f;
  const int lr = hi * 4;  // C/D: row=(lane>>4)*4+reg, col=lane&15
#pragma unroll
  for (int n = 0; n < 4; ++n) {
    int gcol = c0 + wn * 64 + n * 16 + l15;
    float bq = rintf(bias[gcol] * S) * IS;
#pragma unroll
    for (int m = 0; m < 4; ++m) {
      int grow = r0 + wm * 64 + m * 16 + lr;
      float* outp = C + (size_t)grow * N_DIM + gcol;
#pragma unroll
      for (int r = 0; r < 4; ++r) {
        float t = rintf(acc[m][n][r] * S) * IS + bq;
        t = t > 0.0f ? t : 0.0f;
        outp[(size_t)r * N_DIM] = t;
      }
    }
  }
#undef GL
#undef STAGE_A
#undef TILE_BODY
}

// ---- fallback (small workspace): round-1 reg-staged kernel ----
__global__ __launch_bounds__(256, 2) void gemm_fb_kernel(
    const float* __restrict__ Xf, const float* __restrict__ Wf,
    const float* __restrict__ bias, float* __restrict__ C) {
  __shared__ unsigned short As[128][64];
  __shared__ unsigned short Bs[128][64];
  int tid = threadIdx.x;
  int lane = tid & 63;
  int wid = tid >> 6;
  int wr = wid >> 1, wc = wid & 1;
  int r0 = blockIdx.y * 128;
  int c0 = blockIdx.x * 128;
  f32x4 acc[4][4] = {};
  for (int kt = 0; kt < K_DIM / 64; ++kt) {
    __syncthreads();
    int ar = tid >> 1;
    int ac = (tid & 1) * 32;
    const float* xp = Xf + (size_t)(r0 + ar) * K_DIM + kt * 64 + ac;
#pragma unroll
    for (int jj = 0; jj < 8; ++jj) {
      f32x4 v = *(const f32x4*)(xp + jj * 4);
      As[ar][ac + jj * 4 + 0] = f32_to_bf16(v[0]);
      As[ar][ac + jj * 4 + 1] = f32_to_bf16(v[1]);
      As[ar][ac + jj * 4 + 2] = f32_to_bf16(v[2]);
      As[ar][ac + jj * 4 + 3] = f32_to_bf16(v[3]);
    }
    int bk_ = tid >> 2;
    int bc = (tid & 3) * 32;
    const float* wp = Wf + (size_t)(kt * 64 + bk_) * N_DIM + c0 + bc;
#pragma unroll
    for (int jj = 0; jj < 8; ++jj) {
      f32x4 v = *(const f32x4*)(wp + jj * 4);
      Bs[bc + jj * 4 + 0][bk_] = f32_to_bf16(v[0]);
      Bs[bc + jj * 4 + 1][bk_] = f32_to_bf16(v[1]);
      Bs[bc + jj * 4 + 2][bk_] = f32_to_bf16(v[2]);
      Bs[bc + jj * 4 + 3][bk_] = f32_to_bf16(v[3]);
    }
    __syncthreads();
#pragma unroll
    for (int ks = 0; ks < 2; ++ks) {
      int co = ks * 32 + (lane >> 4) * 8;
      int rA = wr * 64 + (lane & 15);
      int rB = wc * 64 + (lane & 15);
      short8 a[4], b[4];
#pragma unroll
      for (int m = 0; m < 4; ++m) a[m] = *(const short8*)&As[rA + m * 16][co];
#pragma unroll
      for (int n = 0; n < 4; ++n) b[n] = *(const short8*)&Bs[rB + n * 16][co];
#pragma unroll
      for (int m = 0; m < 4; ++m)
#pragma unroll
        for (int n = 0; n < 4; ++n)
          acc[m][n] = __builtin_amdgcn_mfma_f32_16x16x32_bf16(a[m], b[n], acc[m][n], 0, 0, 0);
    }
  }
  const float S = 65536.0f, IS = 1.0f / 65536.0f;
  int lr = (lane >> 4) * 4;
  int lc = lane & 15;
#pragma unroll
  for (int n = 0; n < 4; ++n) {
    int gcol = c0 + wc * 64 + n * 16 + lc;
    float bq = rintf(bias[gcol] * S) * IS;
#pragma unroll
    for (int m = 0; m < 4; ++m) {
      int grow = r0 + wr * 64 + m * 16 + lr;
      float* outp = C + (size_t)grow * N_DIM + gcol;
#pragma unroll
      for (int r = 0; r < 4; ++r) {
        float t = rintf(acc[m][n][r] * S) * IS + bq;
        t = t > 0.0f ? t : 0.0f;
        outp[(size_t)r * N_DIM] = t;
      }
    }
  }
}

extern "C" void kernel_launch(void* const* d_in, const int* in_sizes, int n_in,
                              void* d_out, int out_size, void* d_ws, size_t ws_size,
                              hipStream_t stream) {
  const float* x = (const float*)d_in[0];
  const float* w = (const float*)d_in[1];
  const float* b = (const float*)d_in[2];
  float* out = (float*)d_out;

  size_t needA = (size_t)M_DIM * K_DIM * sizeof(unsigned short);
  size_t needB = (size_t)K_DIM * N_DIM * sizeof(unsigned short);

  if (ws_size >= needA + needB) {
    unsigned short* Abf = (unsigned short*)d_ws;
    unsigned short* Bfr = (unsigned short*)((char*)d_ws + needA);
    cvt_x_kernel<<<(M_DIM * (size_t)K_DIM / 8 + 255) / 256, 256, 0, stream>>>(x, Abf);
    bfrag_w_kernel<<<dim3(N_DIM / 64, K_DIM / 64), 256, 0, stream>>>(w, Bfr);
    gemm8_kernel<<<256, 512, 0, stream>>>(Abf, (const char*)Bfr, b, out);
  } else {
    gemm_fb_kernel<<<dim3(N_DIM / 128, M_DIM / 128), 256, 0, stream>>>(x, w, b, out);
  }
}

// Round 6
// 95.813 us; speedup vs baseline: 1.0777x; 1.0777x over previous
//
#include <hip/hip_runtime.h>
#include <hip/hip_bf16.h>
#include <stdint.h>

#define M_DIM 2048
#define N_DIM 4096
#define K_DIM 4096

#define NT 64  // K tiles of 64

typedef short short8 __attribute__((ext_vector_type(8)));
typedef float f32x4 __attribute__((ext_vector_type(4)));

typedef __attribute__((address_space(1))) unsigned int gu32;
typedef __attribute__((address_space(3))) unsigned int lu32;

// f32 -> bf16 round-to-nearest-even
__device__ static inline unsigned short f32_to_bf16(float f) {
  union { float f; unsigned int u; } v; v.f = f;
  unsigned int u = v.u;
  u += 0x7FFFu + ((u >> 16) & 1u);
  return (unsigned short)(u >> 16);
}

// ---- x: f32 [M][K] -> bf16 [M][K] ----
__global__ void cvt_x_kernel(const float* __restrict__ in, unsigned short* __restrict__ out) {
  size_t i = ((size_t)blockIdx.x * blockDim.x + threadIdx.x) * 8;
  f32x4 a = *(const f32x4*)(in + i);
  f32x4 b = *(const f32x4*)(in + i + 4);
  short8 o;
  o[0] = (short)f32_to_bf16(a[0]); o[1] = (short)f32_to_bf16(a[1]);
  o[2] = (short)f32_to_bf16(a[2]); o[3] = (short)f32_to_bf16(a[3]);
  o[4] = (short)f32_to_bf16(b[0]); o[5] = (short)f32_to_bf16(b[1]);
  o[6] = (short)f32_to_bf16(b[2]); o[7] = (short)f32_to_bf16(b[3]);
  *(short8*)(out + i) = o;
}

// ---- w: f32 [K][N] -> bf16 Bt [N][K] ----
__global__ void transpose_cvt_w_kernel(const float* __restrict__ w, unsigned short* __restrict__ wt) {
  __shared__ unsigned short tile[64][64 + 8];
  int bn = blockIdx.x * 64;
  int bk = blockIdx.y * 64;
  int t = threadIdx.x;
  int c4 = (t & 15) * 4;
  int r0 = t >> 4;
#pragma unroll
  for (int p = 0; p < 4; ++p) {
    int r = r0 + p * 16;
    f32x4 v = *(const f32x4*)(w + (size_t)(bk + r) * N_DIM + bn + c4);
    tile[c4 + 0][r] = f32_to_bf16(v[0]);
    tile[c4 + 1][r] = f32_to_bf16(v[1]);
    tile[c4 + 2][r] = f32_to_bf16(v[2]);
    tile[c4 + 3][r] = f32_to_bf16(v[3]);
  }
  __syncthreads();
  int orow = t >> 2;
  int oc = (t & 3) * 16;
  short8 lo, hi;
#pragma unroll
  for (int j = 0; j < 8; ++j) {
    lo[j] = (short)tile[orow][oc + j];
    hi[j] = (short)tile[orow][oc + 8 + j];
  }
  unsigned short* op = wt + (size_t)(bn + orow) * K_DIM + bk + oc;
  *(short8*)(op) = lo;
  *(short8*)(op + 8) = hi;
}

// ============== GEMM (round 6): 4 waves, 64x128 wave tiles ==============
// BM=128, BN=256, BK=64. 256 threads = 4 waves (2M x 2N), wave tile 64x128.
// LDS read traffic per tile: 4 waves x (A 8KB + B 16KB) = 96KB (was 128KB
// with 8 waves of 64x64 -- each A byte now read by 2 waves not 4).
// + staging 48KB => 144KB on the port (~1694 cyc @85B/cyc) vs MFMA 1242.
// A+B: LDS, 3 sides x 48KB = 144KB. Side t%3; stage t+2 into (t-1)%3.
// 12 global_load_lds per thread per tile => top-of-tile vmcnt(12) keeps
// exactly the t+1 stages in flight while guaranteeing tile t staged.
// Sync invariants as round 3/4: per-wave {vmcnt lgkmcnt(0)} then s_barrier
// publishes staging chip-wide before any ds_read; WAR on side (t-1)%3 safe
// because all waves' reads of it completed before their top-of-t lgkmcnt(0).
// XOR swizzle unchanged (slot = chunk ^ (row&7)); bank conflicts 0.

__global__ __launch_bounds__(256, 1) void gemm4_kernel(
    const unsigned short* __restrict__ A, const unsigned short* __restrict__ Bt,
    const float* __restrict__ bias, float* __restrict__ C) {
  __shared__ unsigned short smA[3 * 24576];  // 147456 B
  char* smemc = (char*)&smA[0];

  const int tid = threadIdx.x;
  const int lane = tid & 63;
  const int w = tid >> 6;              // 0..3
  const int wm = w >> 1, wn = w & 1;   // 2x2 wave grid

  // 8x4 region remap for L2 locality (bijective over 256 blocks)
  const int id = blockIdx.x;
  const int x = id & 7, j = id >> 3;
  const int by = ((x >> 2) << 3) + (j >> 2);
  const int bx = ((x & 3) << 2) + (j & 3);
  const int r0 = by * 128, c0 = bx * 256;

  // ---- staging precompute (pre-swizzled global source, linear LDS dest) ----
  const int l8 = lane >> 3, l7 = lane & 7;
  const int chunkE = ((l7 ^ l8) << 3);  // swizzled k-chunk (bf16 elems), row&7 == l8
  const unsigned short* Ag = A + (size_t)(r0 + w * 32 + l8) * K_DIM + chunkE;
  const unsigned short* Bg = Bt + (size_t)(c0 + w * 64 + l8) * K_DIM + chunkE;

#define GL(gp, ldsoff) __builtin_amdgcn_global_load_lds((gu32*)(gp), (lu32*)(smemc + (ldsoff)), 16, 0, 0)
  // wave w stages A rows [w*32, w*32+32) and B rows [w*64, w*64+64): 12 instrs
  auto STAGE = [&](int T, int sb) {
#pragma unroll
    for (int i = 0; i < 4; ++i)
      GL(Ag + (size_t)T * 64 + (size_t)i * 8 * K_DIM, sb + w * 4096 + i * 1024);
#pragma unroll
    for (int i = 0; i < 8; ++i)
      GL(Bg + (size_t)T * 64 + (size_t)i * 8 * K_DIM, sb + 16384 + w * 8192 + i * 1024);
  };

  // ---- fragment-read precompute (ushort units within side) ----
  const int l15 = lane & 15, hi = lane >> 4;
  const int aR = (wm * 64 + l15) * 64;          // A row base (row stride 64 ush)
  const int bR = 8192 + (wn * 128 + l15) * 64;  // B row base (B region at 16KB)
  const int slot0 = ((hi ^ l7) << 3);           // ks=0: chunk hi at slot hi^(row&7)
  const int slot1 = (((4 + hi) ^ l7) << 3);     // ks=1: chunk 4+hi

  f32x4 acc[4][8] = {};

  // prologue: stage tiles 0 and 1 (24 outstanding; vmcnt(12) at t=0 waits tile 0)
  STAGE(0, 0);
  STAGE(1, 49152);

  int cs = 0;  // side of tile t
  for (int t = 0; t < NT; ++t) {
    const int sE = cs * 24576;                       // compute side (ushorts)
    const int stB = (cs == 0 ? 2 : cs - 1) * 49152;  // stage side (bytes)

    if (t < NT - 1) asm volatile("s_waitcnt vmcnt(12) lgkmcnt(0)" ::: "memory");
    else            asm volatile("s_waitcnt vmcnt(0) lgkmcnt(0)" ::: "memory");
    __builtin_amdgcn_sched_barrier(0);
    asm volatile("s_barrier" ::: "memory");

    short8 a0[4], b0[8];
#pragma unroll
    for (int m = 0; m < 4; ++m) a0[m] = *(const short8*)(smA + sE + aR + m * 1024 + slot0);
#pragma unroll
    for (int n = 0; n < 8; ++n) b0[n] = *(const short8*)(smA + sE + bR + n * 1024 + slot0);
    if (t + 2 < NT) STAGE(t + 2, stB);

    __builtin_amdgcn_s_setprio(1);
#pragma unroll
    for (int m = 0; m < 4; ++m)
#pragma unroll
      for (int n = 0; n < 8; ++n)
        acc[m][n] = __builtin_amdgcn_mfma_f32_16x16x32_bf16(a0[m], b0[n], acc[m][n], 0, 0, 0);
    __builtin_amdgcn_s_setprio(0);

    short8 a1[4], b1[8];
#pragma unroll
    for (int m = 0; m < 4; ++m) a1[m] = *(const short8*)(smA + sE + aR + m * 1024 + slot1);
#pragma unroll
    for (int n = 0; n < 8; ++n) b1[n] = *(const short8*)(smA + sE + bR + n * 1024 + slot1);

    __builtin_amdgcn_s_setprio(1);
#pragma unroll
    for (int m = 0; m < 4; ++m)
#pragma unroll
      for (int n = 0; n < 8; ++n)
        acc[m][n] = __builtin_amdgcn_mfma_f32_16x16x32_bf16(a1[m], b1[n], acc[m][n], 0, 0, 0);
    __builtin_amdgcn_s_setprio(0);

    cs = (cs == 2) ? 0 : cs + 1;
  }

  // ---- epilogue: fxp(y) + fxp(b), relu ----
  const float S = 65536.0f, IS = 1.0f / 65536.0f;
  const int lr = hi * 4;  // C/D: row=(lane>>4)*4+reg, col=lane&15
#pragma unroll
  for (int n = 0; n < 8; ++n) {
    int gcol = c0 + wn * 128 + n * 16 + l15;
    float bq = rintf(bias[gcol] * S) * IS;
#pragma unroll
    for (int m = 0; m < 4; ++m) {
      int grow = r0 + wm * 64 + m * 16 + lr;
      float* outp = C + (size_t)grow * N_DIM + gcol;
#pragma unroll
      for (int r = 0; r < 4; ++r) {
        float t = rintf(acc[m][n][r] * S) * IS + bq;
        t = t > 0.0f ? t : 0.0f;
        outp[(size_t)r * N_DIM] = t;
      }
    }
  }
#undef GL
}

// ---- fallback (small workspace): round-1 reg-staged kernel ----
__global__ __launch_bounds__(256, 2) void gemm_fb_kernel(
    const float* __restrict__ Xf, const float* __restrict__ Wf,
    const float* __restrict__ bias, float* __restrict__ C) {
  __shared__ unsigned short As[128][64];
  __shared__ unsigned short Bs[128][64];
  int tid = threadIdx.x;
  int lane = tid & 63;
  int wid = tid >> 6;
  int wr = wid >> 1, wc = wid & 1;
  int r0 = blockIdx.y * 128;
  int c0 = blockIdx.x * 128;
  f32x4 acc[4][4] = {};
  for (int kt = 0; kt < K_DIM / 64; ++kt) {
    __syncthreads();
    int ar = tid >> 1;
    int ac = (tid & 1) * 32;
    const float* xp = Xf + (size_t)(r0 + ar) * K_DIM + kt * 64 + ac;
#pragma unroll
    for (int jj = 0; jj < 8; ++jj) {
      f32x4 v = *(const f32x4*)(xp + jj * 4);
      As[ar][ac + jj * 4 + 0] = f32_to_bf16(v[0]);
      As[ar][ac + jj * 4 + 1] = f32_to_bf16(v[1]);
      As[ar][ac + jj * 4 + 2] = f32_to_bf16(v[2]);
      As[ar][ac + jj * 4 + 3] = f32_to_bf16(v[3]);
    }
    int bk_ = tid >> 2;
    int bc = (tid & 3) * 32;
    const float* wp = Wf + (size_t)(kt * 64 + bk_) * N_DIM + c0 + bc;
#pragma unroll
    for (int jj = 0; jj < 8; ++jj) {
      f32x4 v = *(const f32x4*)(wp + jj * 4);
      Bs[bc + jj * 4 + 0][bk_] = f32_to_bf16(v[0]);
      Bs[bc + jj * 4 + 1][bk_] = f32_to_bf16(v[1]);
      Bs[bc + jj * 4 + 2][bk_] = f32_to_bf16(v[2]);
      Bs[bc + jj * 4 + 3][bk_] = f32_to_bf16(v[3]);
    }
    __syncthreads();
#pragma unroll
    for (int ks = 0; ks < 2; ++ks) {
      int co = ks * 32 + (lane >> 4) * 8;
      int rA = wr * 64 + (lane & 15);
      int rB = wc * 64 + (lane & 15);
      short8 a[4], b[4];
#pragma unroll
      for (int m = 0; m < 4; ++m) a[m] = *(const short8*)&As[rA + m * 16][co];
#pragma unroll
      for (int n = 0; n < 4; ++n) b[n] = *(const short8*)&Bs[rB + n * 16][co];
#pragma unroll
      for (int m = 0; m < 4; ++m)
#pragma unroll
        for (int n = 0; n < 4; ++n)
          acc[m][n] = __builtin_amdgcn_mfma_f32_16x16x32_bf16(a[m], b[n], acc[m][n], 0, 0, 0);
    }
  }
  const float S = 65536.0f, IS = 1.0f / 65536.0f;
  int lr = (lane >> 4) * 4;
  int lc = lane & 15;
#pragma unroll
  for (int n = 0; n < 4; ++n) {
    int gcol = c0 + wc * 64 + n * 16 + lc;
    float bq = rintf(bias[gcol] * S) * IS;
#pragma unroll
    for (int m = 0; m < 4; ++m) {
      int grow = r0 + wr * 64 + m * 16 + lr;
      float* outp = C + (size_t)grow * N_DIM + gcol;
#pragma unroll
      for (int r = 0; r < 4; ++r) {
        float t = rintf(acc[m][n][r] * S) * IS + bq;
        t = t > 0.0f ? t : 0.0f;
        outp[(size_t)r * N_DIM] = t;
      }
    }
  }
}

extern "C" void kernel_launch(void* const* d_in, const int* in_sizes, int n_in,
                              void* d_out, int out_size, void* d_ws, size_t ws_size,
                              hipStream_t stream) {
  const float* x = (const float*)d_in[0];
  const float* w = (const float*)d_in[1];
  const float* b = (const float*)d_in[2];
  float* out = (float*)d_out;

  size_t needA = (size_t)M_DIM * K_DIM * sizeof(unsigned short);
  size_t needB = (size_t)K_DIM * N_DIM * sizeof(unsigned short);

  if (ws_size >= needA + needB) {
    unsigned short* Abf = (unsigned short*)d_ws;
    unsigned short* Btbf = (unsigned short*)((char*)d_ws + needA);
    cvt_x_kernel<<<(M_DIM * (size_t)K_DIM / 8 + 255) / 256, 256, 0, stream>>>(x, Abf);
    transpose_cvt_w_kernel<<<dim3(N_DIM / 64, K_DIM / 64), 256, 0, stream>>>(w, Btbf);
    gemm4_kernel<<<256, 256, 0, stream>>>(Abf, Btbf, b, out);
  } else {
    gemm_fb_kernel<<<dim3(N_DIM / 128, M_DIM / 128), 256, 0, stream>>>(x, w, b, out);
  }
}

// Round 7
// 90.700 us; speedup vs baseline: 1.1384x; 1.0564x over previous
//
#include <hip/hip_runtime.h>
#include <hip/hip_bf16.h>
#include <stdint.h>

#define M_DIM 2048
#define N_DIM 4096
#define K_DIM 4096

#define NT 64  // K tiles of 64

typedef short short8 __attribute__((ext_vector_type(8)));
typedef float f32x4 __attribute__((ext_vector_type(4)));

typedef __attribute__((address_space(1))) unsigned int gu32;
typedef __attribute__((address_space(3))) unsigned int lu32;

// f32 -> bf16 round-to-nearest-even
__device__ static inline unsigned short f32_to_bf16(float f) {
  union { float f; unsigned int u; } v; v.f = f;
  unsigned int u = v.u;
  u += 0x7FFFu + ((u >> 16) & 1u);
  return (unsigned short)(u >> 16);
}

// ---- x: f32 [M][K] -> bf16 [M][K] ----
__global__ void cvt_x_kernel(const float* __restrict__ in, unsigned short* __restrict__ out) {
  size_t i = ((size_t)blockIdx.x * blockDim.x + threadIdx.x) * 8;
  f32x4 a = *(const f32x4*)(in + i);
  f32x4 b = *(const f32x4*)(in + i + 4);
  short8 o;
  o[0] = (short)f32_to_bf16(a[0]); o[1] = (short)f32_to_bf16(a[1]);
  o[2] = (short)f32_to_bf16(a[2]); o[3] = (short)f32_to_bf16(a[3]);
  o[4] = (short)f32_to_bf16(b[0]); o[5] = (short)f32_to_bf16(b[1]);
  o[6] = (short)f32_to_bf16(b[2]); o[7] = (short)f32_to_bf16(b[3]);
  *(short8*)(out + i) = o;
}

// ---- w: f32 [K][N] -> bf16 Bt [N][K] ----
__global__ void transpose_cvt_w_kernel(const float* __restrict__ w, unsigned short* __restrict__ wt) {
  __shared__ unsigned short tile[64][64 + 8];
  int bn = blockIdx.x * 64;
  int bk = blockIdx.y * 64;
  int t = threadIdx.x;
  int c4 = (t & 15) * 4;
  int r0 = t >> 4;
#pragma unroll
  for (int p = 0; p < 4; ++p) {
    int r = r0 + p * 16;
    f32x4 v = *(const f32x4*)(w + (size_t)(bk + r) * N_DIM + bn + c4);
    tile[c4 + 0][r] = f32_to_bf16(v[0]);
    tile[c4 + 1][r] = f32_to_bf16(v[1]);
    tile[c4 + 2][r] = f32_to_bf16(v[2]);
    tile[c4 + 3][r] = f32_to_bf16(v[3]);
  }
  __syncthreads();
  int orow = t >> 2;
  int oc = (t & 3) * 16;
  short8 lo, hi;
#pragma unroll
  for (int j = 0; j < 8; ++j) {
    lo[j] = (short)tile[orow][oc + j];
    hi[j] = (short)tile[orow][oc + 8 + j];
  }
  unsigned short* op = wt + (size_t)(bn + orow) * K_DIM + bk + oc;
  *(short8*)(op) = lo;
  *(short8*)(op + 8) = hi;
}

// ============ GEMM (round 7): R4 skeleton + forced interleave ============
// BM=128, BN=256, BK=64. 512 threads = 8 waves (2M x 4N), wave tile 64x64.
// LDS: 3 sides x 48KB. Side t%3; stage t+2 into (t-1)%3 during body t.
// Sync skeleton identical to R4 (proven): per-wave {vmcnt(6) lgkmcnt(0)}
// then s_barrier publishes tile t chip-wide before any ds_read of side t;
// WAR on side (t-1)%3 covered by the same lgkmcnt(0)+barrier.
// New this round:
//  (1) sched_group_barrier pinning: {8 reads, 6 GL} then {2 MFMA + 1 read}x8
//      then 16 MFMA -- ks1 reads issue under ks0 MFMAs (port never idles).
//  (2) 12 precomputed LDS base pointers (side x ks, A/B); 4 cndmask-selects
//      per tile; ds_read offsets become compile-time immediates (VALU cut).
//  (3) sched_barrier(0) dropped ("memory" clobbers already order LDS/VMEM).

__global__ __launch_bounds__(512) void gemm8_kernel(
    const unsigned short* __restrict__ A, const unsigned short* __restrict__ Bt,
    const float* __restrict__ bias, float* __restrict__ C) {
  __shared__ unsigned short smA[3 * 24576];  // 147456 B
  char* smemc = (char*)&smA[0];

  const int tid = threadIdx.x;
  const int lane = tid & 63;
  const int w = tid >> 6;
  const int wm = w >> 2, wn = w & 3;

  // 8x4 region remap for L2 locality (bijective over 256 blocks)
  const int id = blockIdx.x;
  const int x = id & 7, j = id >> 3;
  const int by = ((x >> 2) << 3) + (j >> 2);
  const int bx = ((x & 3) << 2) + (j & 3);
  const int r0 = by * 128, c0 = bx * 256;

  // ---- staging precompute (pre-swizzled global source, linear LDS dest) ----
  const int l8 = lane >> 3, l7 = lane & 7;
  const int chunkE = ((l7 ^ l8) << 3);  // swizzled k-chunk (bf16 elems), row&7 == l8
  const unsigned short* Ag = A + (size_t)(r0 + w * 16 + l8) * K_DIM + chunkE;
  const unsigned short* Bg = Bt + (size_t)(c0 + w * 32 + l8) * K_DIM + chunkE;
  const int aL0 = w * 2048;          // byte offset of wave's A chunk within side
  const int bL0 = 16384 + w * 4096;  // byte offset of wave's B chunk within side

#define GL(gp, ldsoff) __builtin_amdgcn_global_load_lds((gu32*)(gp), (lu32*)(smemc + (ldsoff)), 16, 0, 0)
#define STAGE_ALL(t, sb)                                               \
  do {                                                                 \
    GL(Ag + (size_t)(t) * 64, (sb) + aL0);                             \
    GL(Ag + (size_t)(t) * 64 + 8 * (size_t)K_DIM, (sb) + aL0 + 1024);  \
    GL(Bg + (size_t)(t) * 64, (sb) + bL0);                             \
    GL(Bg + (size_t)(t) * 64 + 8 * (size_t)K_DIM, (sb) + bL0 + 1024);  \
    GL(Bg + (size_t)(t) * 64 + 16 * (size_t)K_DIM, (sb) + bL0 + 2048); \
    GL(Bg + (size_t)(t) * 64 + 24 * (size_t)K_DIM, (sb) + bL0 + 3072); \
  } while (0)

  // ---- fragment-read precompute: 12 base pointers (side x ks x {A,B}) ----
  const int l15 = lane & 15, hi = lane >> 4;
  const int aR = (wm * 64 + l15) * 64;         // A row base (ushorts)
  const int bR = 8192 + (wn * 64 + l15) * 64;  // B row base (B region at 16KB)
  const int slot0 = ((hi ^ l7) << 3);          // ks=0: chunk hi at slot hi^(row&7)
  const int slot1 = (((4 + hi) ^ l7) << 3);    // ks=1: chunk 4+hi
  const unsigned short* pA0s0 = smA + 0 * 24576 + aR + slot0;
  const unsigned short* pA1s0 = smA + 1 * 24576 + aR + slot0;
  const unsigned short* pA2s0 = smA + 2 * 24576 + aR + slot0;
  const unsigned short* pA0s1 = smA + 0 * 24576 + aR + slot1;
  const unsigned short* pA1s1 = smA + 1 * 24576 + aR + slot1;
  const unsigned short* pA2s1 = smA + 2 * 24576 + aR + slot1;
  const unsigned short* pB0s0 = smA + 0 * 24576 + bR + slot0;
  const unsigned short* pB1s0 = smA + 1 * 24576 + bR + slot0;
  const unsigned short* pB2s0 = smA + 2 * 24576 + bR + slot0;
  const unsigned short* pB0s1 = smA + 0 * 24576 + bR + slot1;
  const unsigned short* pB1s1 = smA + 1 * 24576 + bR + slot1;
  const unsigned short* pB2s1 = smA + 2 * 24576 + bR + slot1;

  f32x4 acc[4][4] = {};

  // prologue: stage tiles 0 and 1
  STAGE_ALL(0, 0);
  STAGE_ALL(1, 49152);

#define SGB __builtin_amdgcn_sched_group_barrier
  int cs = 0;  // side of tile t
  for (int t = 0; t < NT; ++t) {
    const int stB = (cs == 0 ? 2 : cs - 1) * 49152;  // stage side (bytes)
    const bool doStage = (t + 2) < NT;

    // select this side's 4 fragment base pointers (2 cndmask pairs each)
    const unsigned short* pAs0 = (cs == 0) ? pA0s0 : (cs == 1) ? pA1s0 : pA2s0;
    const unsigned short* pAs1 = (cs == 0) ? pA0s1 : (cs == 1) ? pA1s1 : pA2s1;
    const unsigned short* pBs0 = (cs == 0) ? pB0s0 : (cs == 1) ? pB1s0 : pB2s0;
    const unsigned short* pBs1 = (cs == 0) ? pB0s1 : (cs == 1) ? pB1s1 : pB2s1;

    // per-wave completion of tile t's loads, published to all waves
    if (t < NT - 1) asm volatile("s_waitcnt vmcnt(6) lgkmcnt(0)" ::: "memory");
    else            asm volatile("s_waitcnt vmcnt(0) lgkmcnt(0)" ::: "memory");
    asm volatile("s_barrier" ::: "memory");

    // -------- body: reads + stage + MFMA with pinned interleave --------
    short8 a0[4], b0[4], a1[4], b1[4];
#pragma unroll
    for (int m = 0; m < 4; ++m) a0[m] = *(const short8*)(pAs0 + m * 1024);
#pragma unroll
    for (int n = 0; n < 4; ++n) b0[n] = *(const short8*)(pBs0 + n * 1024);
    if (doStage) STAGE_ALL(t + 2, stB);
#pragma unroll
    for (int m = 0; m < 4; ++m) a1[m] = *(const short8*)(pAs1 + m * 1024);
#pragma unroll
    for (int n = 0; n < 4; ++n) b1[n] = *(const short8*)(pBs1 + n * 1024);

    __builtin_amdgcn_s_setprio(1);
#pragma unroll
    for (int m = 0; m < 4; ++m)
#pragma unroll
      for (int n = 0; n < 4; ++n)
        acc[m][n] = __builtin_amdgcn_mfma_f32_16x16x32_bf16(a0[m], b0[n], acc[m][n], 0, 0, 0);
#pragma unroll
    for (int m = 0; m < 4; ++m)
#pragma unroll
      for (int n = 0; n < 4; ++n)
        acc[m][n] = __builtin_amdgcn_mfma_f32_16x16x32_bf16(a1[m], b1[n], acc[m][n], 0, 0, 0);
    __builtin_amdgcn_s_setprio(0);

    // ---- scheduler pinning for the whole body region ----
    // front: 8 ds_read (a0,b0) + 6 global_load_lds issue
    SGB(0x100, 8, 0);   // DS_READ x8
    SGB(0x020, 6, 0);   // VMEM_READ x6 (global_load_lds)
    // middle: 16 MFMA (ks0) interleaved 2:1 with the 8 remaining ds_read
    SGB(0x008, 2, 0); SGB(0x100, 1, 0);
    SGB(0x008, 2, 0); SGB(0x100, 1, 0);
    SGB(0x008, 2, 0); SGB(0x100, 1, 0);
    SGB(0x008, 2, 0); SGB(0x100, 1, 0);
    SGB(0x008, 2, 0); SGB(0x100, 1, 0);
    SGB(0x008, 2, 0); SGB(0x100, 1, 0);
    SGB(0x008, 2, 0); SGB(0x100, 1, 0);
    SGB(0x008, 2, 0); SGB(0x100, 1, 0);
    // tail: 16 MFMA (ks1)
    SGB(0x008, 16, 0);

    cs = (cs == 2) ? 0 : cs + 1;
  }
#undef SGB

  // ---- epilogue: fxp(y) + fxp(b), relu ----
  const float S = 65536.0f, IS = 1.0f / 65536.0f;
  const int lr = hi * 4;  // C/D: row=(lane>>4)*4+reg, col=lane&15
#pragma unroll
  for (int n = 0; n < 4; ++n) {
    int gcol = c0 + wn * 64 + n * 16 + l15;
    float bq = rintf(bias[gcol] * S) * IS;
#pragma unroll
    for (int m = 0; m < 4; ++m) {
      int grow = r0 + wm * 64 + m * 16 + lr;
      float* outp = C + (size_t)grow * N_DIM + gcol;
#pragma unroll
      for (int r = 0; r < 4; ++r) {
        float t = rintf(acc[m][n][r] * S) * IS + bq;
        t = t > 0.0f ? t : 0.0f;
        outp[(size_t)r * N_DIM] = t;
      }
    }
  }
#undef GL
#undef STAGE_ALL
}

// ---- fallback (small workspace): round-1 reg-staged kernel ----
__global__ __launch_bounds__(256, 2) void gemm_fb_kernel(
    const float* __restrict__ Xf, const float* __restrict__ Wf,
    const float* __restrict__ bias, float* __restrict__ C) {
  __shared__ unsigned short As[128][64];
  __shared__ unsigned short Bs[128][64];
  int tid = threadIdx.x;
  int lane = tid & 63;
  int wid = tid >> 6;
  int wr = wid >> 1, wc = wid & 1;
  int r0 = blockIdx.y * 128;
  int c0 = blockIdx.x * 128;
  f32x4 acc[4][4] = {};
  for (int kt = 0; kt < K_DIM / 64; ++kt) {
    __syncthreads();
    int ar = tid >> 1;
    int ac = (tid & 1) * 32;
    const float* xp = Xf + (size_t)(r0 + ar) * K_DIM + kt * 64 + ac;
#pragma unroll
    for (int jj = 0; jj < 8; ++jj) {
      f32x4 v = *(const f32x4*)(xp + jj * 4);
      As[ar][ac + jj * 4 + 0] = f32_to_bf16(v[0]);
      As[ar][ac + jj * 4 + 1] = f32_to_bf16(v[1]);
      As[ar][ac + jj * 4 + 2] = f32_to_bf16(v[2]);
      As[ar][ac + jj * 4 + 3] = f32_to_bf16(v[3]);
    }
    int bk_ = tid >> 2;
    int bc = (tid & 3) * 32;
    const float* wp = Wf + (size_t)(kt * 64 + bk_) * N_DIM + c0 + bc;
#pragma unroll
    for (int jj = 0; jj < 8; ++jj) {
      f32x4 v = *(const f32x4*)(wp + jj * 4);
      Bs[bc + jj * 4 + 0][bk_] = f32_to_bf16(v[0]);
      Bs[bc + jj * 4 + 1][bk_] = f32_to_bf16(v[1]);
      Bs[bc + jj * 4 + 2][bk_] = f32_to_bf16(v[2]);
      Bs[bc + jj * 4 + 3][bk_] = f32_to_bf16(v[3]);
    }
    __syncthreads();
#pragma unroll
    for (int ks = 0; ks < 2; ++ks) {
      int co = ks * 32 + (lane >> 4) * 8;
      int rA = wr * 64 + (lane & 15);
      int rB = wc * 64 + (lane & 15);
      short8 a[4], b[4];
#pragma unroll
      for (int m = 0; m < 4; ++m) a[m] = *(const short8*)&As[rA + m * 16][co];
#pragma unroll
      for (int n = 0; n < 4; ++n) b[n] = *(const short8*)&Bs[rB + n * 16][co];
#pragma unroll
      for (int m = 0; m < 4; ++m)
#pragma unroll
        for (int n = 0; n < 4; ++n)
          acc[m][n] = __builtin_amdgcn_mfma_f32_16x16x32_bf16(a[m], b[n], acc[m][n], 0, 0, 0);
    }
  }
  const float S = 65536.0f, IS = 1.0f / 65536.0f;
  int lr = (lane >> 4) * 4;
  int lc = lane & 15;
#pragma unroll
  for (int n = 0; n < 4; ++n) {
    int gcol = c0 + wc * 64 + n * 16 + lc;
    float bq = rintf(bias[gcol] * S) * IS;
#pragma unroll
    for (int m = 0; m < 4; ++m) {
      int grow = r0 + wr * 64 + m * 16 + lr;
      float* outp = C + (size_t)grow * N_DIM + gcol;
#pragma unroll
      for (int r = 0; r < 4; ++r) {
        float t = rintf(acc[m][n][r] * S) * IS + bq;
        t = t > 0.0f ? t : 0.0f;
        outp[(size_t)r * N_DIM] = t;
      }
    }
  }
}

extern "C" void kernel_launch(void* const* d_in, const int* in_sizes, int n_in,
                              void* d_out, int out_size, void* d_ws, size_t ws_size,
                              hipStream_t stream) {
  const float* x = (const float*)d_in[0];
  const float* w = (const float*)d_in[1];
  const float* b = (const float*)d_in[2];
  float* out = (float*)d_out;

  size_t needA = (size_t)M_DIM * K_DIM * sizeof(unsigned short);
  size_t needB = (size_t)K_DIM * N_DIM * sizeof(unsigned short);

  if (ws_size >= needA + needB) {
    unsigned short* Abf = (unsigned short*)d_ws;
    unsigned short* Btbf = (unsigned short*)((char*)d_ws + needA);
    cvt_x_kernel<<<(M_DIM * (size_t)K_DIM / 8 + 255) / 256, 256, 0, stream>>>(x, Abf);
    transpose_cvt_w_kernel<<<dim3(N_DIM / 64, K_DIM / 64), 256, 0, stream>>>(w, Btbf);
    gemm8_kernel<<<256, 512, 0, stream>>>(Abf, Btbf, b, out);
  } else {
    gemm_fb_kernel<<<dim3(N_DIM / 128, M_DIM / 128), 256, 0, stream>>>(x, w, b, out);
  }
}

// Round 8
// 88.998 us; speedup vs baseline: 1.1602x; 1.0191x over previous
//
#include <hip/hip_runtime.h>
#include <hip/hip_bf16.h>
#include <stdint.h>

#define M_DIM 2048
#define N_DIM 4096
#define K_DIM 4096

#define NT 64  // K tiles of 64

typedef short short8 __attribute__((ext_vector_type(8)));
typedef float f32x4 __attribute__((ext_vector_type(4)));

typedef __attribute__((address_space(1))) unsigned int gu32;
typedef __attribute__((address_space(3))) unsigned int lu32;

// f32 -> bf16 round-to-nearest-even
__device__ static inline unsigned short f32_to_bf16(float f) {
  union { float f; unsigned int u; } v; v.f = f;
  unsigned int u = v.u;
  u += 0x7FFFu + ((u >> 16) & 1u);
  return (unsigned short)(u >> 16);
}

// ---- x: f32 [M][K] -> bf16 [M][K] ----
__global__ void cvt_x_kernel(const float* __restrict__ in, unsigned short* __restrict__ out) {
  size_t i = ((size_t)blockIdx.x * blockDim.x + threadIdx.x) * 8;
  f32x4 a = *(const f32x4*)(in + i);
  f32x4 b = *(const f32x4*)(in + i + 4);
  short8 o;
  o[0] = (short)f32_to_bf16(a[0]); o[1] = (short)f32_to_bf16(a[1]);
  o[2] = (short)f32_to_bf16(a[2]); o[3] = (short)f32_to_bf16(a[3]);
  o[4] = (short)f32_to_bf16(b[0]); o[5] = (short)f32_to_bf16(b[1]);
  o[6] = (short)f32_to_bf16(b[2]); o[7] = (short)f32_to_bf16(b[3]);
  *(short8*)(out + i) = o;
}

// ---- w: f32 [K][N] -> bf16 Bt [N][K] ----
__global__ void transpose_cvt_w_kernel(const float* __restrict__ w, unsigned short* __restrict__ wt) {
  __shared__ unsigned short tile[64][64 + 8];
  int bn = blockIdx.x * 64;
  int bk = blockIdx.y * 64;
  int t = threadIdx.x;
  int c4 = (t & 15) * 4;
  int r0 = t >> 4;
#pragma unroll
  for (int p = 0; p < 4; ++p) {
    int r = r0 + p * 16;
    f32x4 v = *(const f32x4*)(w + (size_t)(bk + r) * N_DIM + bn + c4);
    tile[c4 + 0][r] = f32_to_bf16(v[0]);
    tile[c4 + 1][r] = f32_to_bf16(v[1]);
    tile[c4 + 2][r] = f32_to_bf16(v[2]);
    tile[c4 + 3][r] = f32_to_bf16(v[3]);
  }
  __syncthreads();
  int orow = t >> 2;
  int oc = (t & 3) * 16;
  short8 lo, hi;
#pragma unroll
  for (int j = 0; j < 8; ++j) {
    lo[j] = (short)tile[orow][oc + j];
    hi[j] = (short)tile[orow][oc + 8 + j];
  }
  unsigned short* op = wt + (size_t)(bn + orow) * K_DIM + bk + oc;
  *(short8*)(op) = lo;
  *(short8*)(op + 8) = hi;
}

// ========== GEMM (round 8): in-block K-split, wave-tile 64x128 ==========
// BM=128, BN=256, BK=64. 512 threads = 8 waves. NEW decomposition:
// 4 output tiles of 64x128 (2x2); tile q owned by wave pair {q, q+4}.
// Wave q computes k-step 0 (k 0..31), wave q+4 k-step 1 (k 32..63).
// Per-wave per-tile LDS reads: A 4KB + B 8KB = 12KB (was 16KB with 64x64
// tiles) -> block reads 96KB/tile (was 128KB); port total 144KB (was 176,
// -18%). MFMA count unchanged (32/wave/tile). Traffic/FLOP is the lever:
// R7 showed schedule pinning is null; port runs ~73 B/cyc like HK's.
// Pair partials summed once at the end via LDS exchange (sides are dead).
// Skeleton (3-side rotation, stage t+2 into (t-1)%3, per-tile
// {vmcnt(6) lgkmcnt(0); s_barrier}, pre-swizzled staging, XOR read slots)
// is byte-identical to the R4/R7 proven version.

__global__ __launch_bounds__(512) void gemm8_kernel(
    const unsigned short* __restrict__ A, const unsigned short* __restrict__ Bt,
    const float* __restrict__ bias, float* __restrict__ C) {
  __shared__ unsigned short smA[3 * 24576];  // 147456 B
  char* smemc = (char*)&smA[0];

  const int tid = threadIdx.x;
  const int lane = tid & 63;
  const int w = tid >> 6;
  const int q = w & 3;          // output tile index (2x2)
  const int half = w >> 2;      // k-step half (0: k0..31, 1: k32..63)
  const int qm = q >> 1, qn = q & 1;

  // 8x4 region remap for L2 locality (bijective over 256 blocks)
  const int id = blockIdx.x;
  const int x = id & 7, j = id >> 3;
  const int by = ((x >> 2) << 3) + (j >> 2);
  const int bx = ((x & 3) << 2) + (j & 3);
  const int r0 = by * 128, c0 = bx * 256;

  // ---- staging precompute (pre-swizzled global source, linear LDS dest) ----
  const int l8 = lane >> 3, l7 = lane & 7;
  const int chunkE = ((l7 ^ l8) << 3);  // swizzled k-chunk (bf16 elems), row&7 == l8
  const unsigned short* Ag = A + (size_t)(r0 + w * 16 + l8) * K_DIM + chunkE;
  const unsigned short* Bg = Bt + (size_t)(c0 + w * 32 + l8) * K_DIM + chunkE;
  const int aL0 = w * 2048;          // byte offset of wave's A chunk within side
  const int bL0 = 16384 + w * 4096;  // byte offset of wave's B chunk within side

#define GL(gp, ldsoff) __builtin_amdgcn_global_load_lds((gu32*)(gp), (lu32*)(smemc + (ldsoff)), 16, 0, 0)
#define STAGE_ALL(t, sb)                                               \
  do {                                                                 \
    GL(Ag + (size_t)(t) * 64, (sb) + aL0);                             \
    GL(Ag + (size_t)(t) * 64 + 8 * (size_t)K_DIM, (sb) + aL0 + 1024);  \
    GL(Bg + (size_t)(t) * 64, (sb) + bL0);                             \
    GL(Bg + (size_t)(t) * 64 + 8 * (size_t)K_DIM, (sb) + bL0 + 1024);  \
    GL(Bg + (size_t)(t) * 64 + 16 * (size_t)K_DIM, (sb) + bL0 + 2048); \
    GL(Bg + (size_t)(t) * 64 + 24 * (size_t)K_DIM, (sb) + bL0 + 3072); \
  } while (0)

  // ---- fragment-read precompute (ushort units within side) ----
  const int l15 = lane & 15, hi = lane >> 4;
  const int aR = (qm * 64 + l15) * 64;          // A row base (row&7 == l7)
  const int bR = 8192 + (qn * 128 + l15) * 64;  // B row base (B region at 16KB)
  const int slotH = (((half << 2) + hi) ^ l7) << 3;  // this wave's k-chunk slot
  const unsigned short* pA0 = smA + 0 * 24576 + aR + slotH;
  const unsigned short* pA1 = smA + 1 * 24576 + aR + slotH;
  const unsigned short* pA2 = smA + 2 * 24576 + aR + slotH;
  const unsigned short* pB0 = smA + 0 * 24576 + bR + slotH;
  const unsigned short* pB1 = smA + 1 * 24576 + bR + slotH;
  const unsigned short* pB2 = smA + 2 * 24576 + bR + slotH;

  f32x4 acc[4][8] = {};

  // prologue: stage tiles 0 and 1
  STAGE_ALL(0, 0);
  STAGE_ALL(1, 49152);

  int cs = 0;  // side of tile t
  for (int t = 0; t < NT; ++t) {
    const int stB = (cs == 0 ? 2 : cs - 1) * 49152;  // stage side (bytes)
    const bool doStage = (t + 2) < NT;

    const unsigned short* pAs = (cs == 0) ? pA0 : (cs == 1) ? pA1 : pA2;
    const unsigned short* pBs = (cs == 0) ? pB0 : (cs == 1) ? pB1 : pB2;

    // per-wave completion of tile t's loads, published to all waves
    if (t < NT - 1) asm volatile("s_waitcnt vmcnt(6) lgkmcnt(0)" ::: "memory");
    else            asm volatile("s_waitcnt vmcnt(0) lgkmcnt(0)" ::: "memory");
    asm volatile("s_barrier" ::: "memory");

    // -------- body: 12 ds_read + 6 GL + 32 MFMA --------
    short8 a[4], b[8];
#pragma unroll
    for (int m = 0; m < 4; ++m) a[m] = *(const short8*)(pAs + m * 1024);
#pragma unroll
    for (int n = 0; n < 8; ++n) b[n] = *(const short8*)(pBs + n * 1024);
    if (doStage) STAGE_ALL(t + 2, stB);

    __builtin_amdgcn_s_setprio(1);
#pragma unroll
    for (int m = 0; m < 4; ++m)
#pragma unroll
      for (int n = 0; n < 8; ++n)
        acc[m][n] = __builtin_amdgcn_mfma_f32_16x16x32_bf16(a[m], b[n], acc[m][n], 0, 0, 0);
    __builtin_amdgcn_s_setprio(0);

    cs = (cs == 2) ? 0 : cs + 1;
  }

  // ---- pair reduction: waves 4-7 hand partials to waves 0-3 via LDS ----
  __syncthreads();
  float* xch = (float*)&smA[0];  // 4 pairs x 32KB = 128KB <= 144KB (sides dead)
  if (half == 1) {
#pragma unroll
    for (int m = 0; m < 4; ++m)
#pragma unroll
      for (int n = 0; n < 8; ++n)
        *(f32x4*)(xch + q * 8192 + (m * 8 + n) * 256 + lane * 4) = acc[m][n];
  }
  __syncthreads();

  if (half == 0) {
    const float S = 65536.0f, IS = 1.0f / 65536.0f;
    const int lr = hi * 4;  // C/D: row=(lane>>4)*4+reg, col=lane&15
#pragma unroll
    for (int n = 0; n < 8; ++n) {
      int gcol = c0 + qn * 128 + n * 16 + l15;
      float bq = rintf(bias[gcol] * S) * IS;
#pragma unroll
      for (int m = 0; m < 4; ++m) {
        f32x4 part = *(const f32x4*)(xch + q * 8192 + (m * 8 + n) * 256 + lane * 4);
        int grow = r0 + qm * 64 + m * 16 + lr;
        float* outp = C + (size_t)grow * N_DIM + gcol;
#pragma unroll
        for (int r = 0; r < 4; ++r) {
          float t = rintf((acc[m][n][r] + part[r]) * S) * IS + bq;
          t = t > 0.0f ? t : 0.0f;
          outp[(size_t)r * N_DIM] = t;
        }
      }
    }
  }
#undef GL
#undef STAGE_ALL
}

// ---- fallback (small workspace): round-1 reg-staged kernel ----
__global__ __launch_bounds__(256, 2) void gemm_fb_kernel(
    const float* __restrict__ Xf, const float* __restrict__ Wf,
    const float* __restrict__ bias, float* __restrict__ C) {
  __shared__ unsigned short As[128][64];
  __shared__ unsigned short Bs[128][64];
  int tid = threadIdx.x;
  int lane = tid & 63;
  int wid = tid >> 6;
  int wr = wid >> 1, wc = wid & 1;
  int r0 = blockIdx.y * 128;
  int c0 = blockIdx.x * 128;
  f32x4 acc[4][4] = {};
  for (int kt = 0; kt < K_DIM / 64; ++kt) {
    __syncthreads();
    int ar = tid >> 1;
    int ac = (tid & 1) * 32;
    const float* xp = Xf + (size_t)(r0 + ar) * K_DIM + kt * 64 + ac;
#pragma unroll
    for (int jj = 0; jj < 8; ++jj) {
      f32x4 v = *(const f32x4*)(xp + jj * 4);
      As[ar][ac + jj * 4 + 0] = f32_to_bf16(v[0]);
      As[ar][ac + jj * 4 + 1] = f32_to_bf16(v[1]);
      As[ar][ac + jj * 4 + 2] = f32_to_bf16(v[2]);
      As[ar][ac + jj * 4 + 3] = f32_to_bf16(v[3]);
    }
    int bk_ = tid >> 2;
    int bc = (tid & 3) * 32;
    const float* wp = Wf + (size_t)(kt * 64 + bk_) * N_DIM + c0 + bc;
#pragma unroll
    for (int jj = 0; jj < 8; ++jj) {
      f32x4 v = *(const f32x4*)(wp + jj * 4);
      Bs[bc + jj * 4 + 0][bk_] = f32_to_bf16(v[0]);
      Bs[bc + jj * 4 + 1][bk_] = f32_to_bf16(v[1]);
      Bs[bc + jj * 4 + 2][bk_] = f32_to_bf16(v[2]);
      Bs[bc + jj * 4 + 3][bk_] = f32_to_bf16(v[3]);
    }
    __syncthreads();
#pragma unroll
    for (int ks = 0; ks < 2; ++ks) {
      int co = ks * 32 + (lane >> 4) * 8;
      int rA = wr * 64 + (lane & 15);
      int rB = wc * 64 + (lane & 15);
      short8 a[4], b[4];
#pragma unroll
      for (int m = 0; m < 4; ++m) a[m] = *(const short8*)&As[rA + m * 16][co];
#pragma unroll
      for (int n = 0; n < 4; ++n) b[n] = *(const short8*)&Bs[rB + n * 16][co];
#pragma unroll
      for (int m = 0; m < 4; ++m)
#pragma unroll
        for (int n = 0; n < 4; ++n)
          acc[m][n] = __builtin_amdgcn_mfma_f32_16x16x32_bf16(a[m], b[n], acc[m][n], 0, 0, 0);
    }
  }
  const float S = 65536.0f, IS = 1.0f / 65536.0f;
  int lr = (lane >> 4) * 4;
  int lc = lane & 15;
#pragma unroll
  for (int n = 0; n < 4; ++n) {
    int gcol = c0 + wc * 64 + n * 16 + lc;
    float bq = rintf(bias[gcol] * S) * IS;
#pragma unroll
    for (int m = 0; m < 4; ++m) {
      int grow = r0 + wr * 64 + m * 16 + lr;
      float* outp = C + (size_t)grow * N_DIM + gcol;
#pragma unroll
      for (int r = 0; r < 4; ++r) {
        float t = rintf(acc[m][n][r] * S) * IS + bq;
        t = t > 0.0f ? t : 0.0f;
        outp[(size_t)r * N_DIM] = t;
      }
    }
  }
}

extern "C" void kernel_launch(void* const* d_in, const int* in_sizes, int n_in,
                              void* d_out, int out_size, void* d_ws, size_t ws_size,
                              hipStream_t stream) {
  const float* x = (const float*)d_in[0];
  const float* w = (const float*)d_in[1];
  const float* b = (const float*)d_in[2];
  float* out = (float*)d_out;

  size_t needA = (size_t)M_DIM * K_DIM * sizeof(unsigned short);
  size_t needB = (size_t)K_DIM * N_DIM * sizeof(unsigned short);

  if (ws_size >= needA + needB) {
    unsigned short* Abf = (unsigned short*)d_ws;
    unsigned short* Btbf = (unsigned short*)((char*)d_ws + needA);
    cvt_x_kernel<<<(M_DIM * (size_t)K_DIM / 8 + 255) / 256, 256, 0, stream>>>(x, Abf);
    transpose_cvt_w_kernel<<<dim3(N_DIM / 64, K_DIM / 64), 256, 0, stream>>>(w, Btbf);
    gemm8_kernel<<<256, 512, 0, stream>>>(Abf, Btbf, b, out);
  } else {
    gemm_fb_kernel<<<dim3(N_DIM / 128, M_DIM / 128), 256, 0, stream>>>(x, w, b, out);
  }
}